// Round 3
// baseline (280.723 us; speedup 1.0000x reference)
//
#include <hip/hip_runtime.h>
#include <hip/hip_bf16.h>

#define EMBED 768
#define HEADS 12
#define WIN 64
#define DH 64
#define KDIM 768
#define NTILE 12      // KDIM / 64

typedef unsigned short u16;
typedef unsigned int u32;
typedef __attribute__((ext_vector_type(8))) short bf16x8;
typedef __attribute__((ext_vector_type(4))) float f32x4;

__device__ __forceinline__ u16 f2bf(float f) {
  union { float f; u32 u; } x; x.f = f;
  return (u16)((x.u + 0x7fffu + ((x.u >> 16) & 1u)) >> 16);
}

// ---------------- fp32 -> bf16 convert ----------------
__global__ void cvt_f32_bf16(const float* __restrict__ in, u16* __restrict__ out, int n4) {
  int i = blockIdx.x * blockDim.x + threadIdx.x;
  if (i >= n4) return;
  float4 v = ((const float4*)in)[i];
  ushort4 o;
  o.x = f2bf(v.x); o.y = f2bf(v.y); o.z = f2bf(v.z); o.w = f2bf(v.w);
  ((ushort4*)out)[i] = o;
}

__global__ void concat_bias(const float* __restrict__ bq, const float* __restrict__ bk,
                            const float* __restrict__ bv, float* __restrict__ out) {
  int i = blockIdx.x * 256 + threadIdx.x;
  if (i < 768) out[i] = bq[i];
  else if (i < 1536) out[i] = bk[i - 768];
  else if (i < 2304) out[i] = bv[i - 1536];
}

// ---------------- 256x256 phase-split pipelined NT GEMM (K=768) ----------------
// C[M,N] = A[M,768] * B[N,768]^T + bias. 512 thr = 8 waves (2M x 4N), per-wave
// 128x64 out (8x4 frags of 16x16x32 bf16). LDS 128KB: A/B x 2 K-tile dbuf.
// T1 XCD swizzle, T2 XOR-swizzled LDS (linear gload_lds dest + pre-swizzled
// global src), T3 4 phases/K-tile, T4 counted vmcnt(8), T5 setprio around MFMA.
template<bool OUT_F32>
__global__ __launch_bounds__(512, 2)
void gemm256(const u16* __restrict__ A, const u16* __restrict__ Bw,
             const float* __restrict__ bias,
             u16* __restrict__ dQ, u16* __restrict__ dK, u16* __restrict__ dV,
             float* __restrict__ dF, int N) {
  __shared__ u16 smem[65536];                    // 128 KiB
  char* sc_ = (char*)smem;
  const int tid = threadIdx.x;
  const int lane = tid & 63;
  const int wid = tid >> 6;
  const int wr = wid >> 2, wc = wid & 3;
  const int l15 = lane & 15;

  const int nbx = N >> 8;
  const int cpx = gridDim.x >> 3;
  int bid = blockIdx.x;
  bid = (bid & 7) * cpx + (bid >> 3);            // bijective: grid % 8 == 0
  const int brow = (bid / nbx) << 8;
  const int bcol = (bid % nbx) << 8;

  // staging source (per-thread): row = 64*i + (tid>>3), chunk = (tid&7) ^ (row&7)
  const int srow = tid >> 3;
  const int scol = ((tid & 7) ^ (srow & 7)) << 3;
  const u16* Asrc = A + (size_t)(brow + srow) * KDIM + scol;
  const u16* Bsrc = Bw + (size_t)(bcol + srow) * KDIM + scol;
  const int lds_woff = wid << 10;                // wave base within each 8KB inst block

  auto STAGE = [&](int b, int kt) {
    char* ab = sc_ + b * 32768;
    char* bb = sc_ + 65536 + b * 32768;
#pragma unroll
    for (int i = 0; i < 4; ++i) {
      __builtin_amdgcn_global_load_lds(
          (const __attribute__((address_space(1))) void*)(Asrc + (size_t)(i << 6) * KDIM + kt),
          (__attribute__((address_space(3))) void*)(ab + (i << 13) + lds_woff), 16, 0, 0);
      __builtin_amdgcn_global_load_lds(
          (const __attribute__((address_space(1))) void*)(Bsrc + (size_t)(i << 6) * KDIM + kt),
          (__attribute__((address_space(3))) void*)(bb + (i << 13) + lds_woff), 16, 0, 0);
    }
  };

  // frag-read byte offsets: row*128 + ((kk*64 + (lane>>4)*16) ^ ((row&7)<<4)); row&7==lane&7
  const int koff0 = ((lane >> 4) << 4) ^ ((lane & 7) << 4);
  const int koff1 = koff0 ^ 64;

  f32x4 acc[8][4];
#pragma unroll
  for (int m = 0; m < 8; ++m)
#pragma unroll
    for (int n = 0; n < 4; ++n) acc[m][n] = (f32x4){0.f, 0.f, 0.f, 0.f};

  STAGE(0, 0);
  STAGE(1, 64);
  asm volatile("s_waitcnt vmcnt(8)" ::: "memory");
  __builtin_amdgcn_s_barrier();

  for (int t = 0; t < NTILE; ++t) {
    const int b = t & 1;
    char* Ab_ = sc_ + b * 32768;
    char* Bb_ = sc_ + 65536 + b * 32768;
    const char* pa0 = Ab_ + (wr << 14) + l15 * 128 + koff0;
    const char* pa1 = Ab_ + (wr << 14) + l15 * 128 + koff1;
    const char* pb0 = Bb_ + (wc << 13) + l15 * 128 + koff0;
    const char* pb1 = Bb_ + (wc << 13) + l15 * 128 + koff1;

    bf16x8 bF[4][2];
#pragma unroll
    for (int nj = 0; nj < 4; ++nj) {
      bF[nj][0] = *(const bf16x8*)(pb0 + nj * 2048);
      bF[nj][1] = *(const bf16x8*)(pb1 + nj * 2048);
    }
#pragma unroll
    for (int q = 0; q < 4; ++q) {
      bf16x8 a00 = *(const bf16x8*)(pa0 + (q * 2) * 2048);
      bf16x8 a01 = *(const bf16x8*)(pa1 + (q * 2) * 2048);
      bf16x8 a10 = *(const bf16x8*)(pa0 + (q * 2 + 1) * 2048);
      bf16x8 a11 = *(const bf16x8*)(pa1 + (q * 2 + 1) * 2048);
      __builtin_amdgcn_s_barrier();
      asm volatile("s_waitcnt lgkmcnt(0)" ::: "memory");
      __builtin_amdgcn_sched_barrier(0);
      __builtin_amdgcn_s_setprio(1);
#pragma unroll
      for (int nj = 0; nj < 4; ++nj) {
        acc[q * 2][nj]     = __builtin_amdgcn_mfma_f32_16x16x32_bf16(a00, bF[nj][0], acc[q * 2][nj], 0, 0, 0);
        acc[q * 2][nj]     = __builtin_amdgcn_mfma_f32_16x16x32_bf16(a01, bF[nj][1], acc[q * 2][nj], 0, 0, 0);
        acc[q * 2 + 1][nj] = __builtin_amdgcn_mfma_f32_16x16x32_bf16(a10, bF[nj][0], acc[q * 2 + 1][nj], 0, 0, 0);
        acc[q * 2 + 1][nj] = __builtin_amdgcn_mfma_f32_16x16x32_bf16(a11, bF[nj][1], acc[q * 2 + 1][nj], 0, 0, 0);
      }
      __builtin_amdgcn_s_setprio(0);
      __builtin_amdgcn_sched_barrier(0);
      __builtin_amdgcn_s_barrier();
    }
    if (t < NTILE - 2) {
      STAGE(b, (t + 2) << 6);                    // overwrite just-consumed buffer
      asm volatile("s_waitcnt vmcnt(8)" ::: "memory");   // tile t+1 landed; t+2 in flight
      __builtin_amdgcn_sched_barrier(0);
      __builtin_amdgcn_s_barrier();
    } else if (t == NTILE - 2) {
      asm volatile("s_waitcnt vmcnt(0)" ::: "memory");   // tail drain
      __builtin_amdgcn_sched_barrier(0);
      __builtin_amdgcn_s_barrier();
    }
  }

  if (!OUT_F32) {
    // bf16 epilogue: stage 256x256 tile (128KB), coalesced 16B stores, QKV split
#pragma unroll
    for (int mi = 0; mi < 8; ++mi)
#pragma unroll
      for (int nj = 0; nj < 4; ++nj) {
        const int colb = (wc << 6) + (nj << 4) + l15;
        const float bb = bias[bcol + colb];
        const int row0 = (wr << 7) + (mi << 4) + ((lane >> 4) << 2);
#pragma unroll
        for (int rr = 0; rr < 4; ++rr)
          smem[((row0 + rr) << 8) + colb] = f2bf(acc[mi][nj][rr] + bb);
      }
    __syncthreads();
    const int seg = bcol / 768;
    const int cb = bcol - seg * 768;
    u16* dst = (seg == 0) ? dQ : (seg == 1) ? dK : dV;
#pragma unroll
    for (int it = 0; it < 16; ++it) {
      const int f = (it << 9) + tid;
      const int row = f >> 5, c8 = f & 31;
      uint4 v = *(const uint4*)(smem + (row << 8) + (c8 << 3));
      *(uint4*)(dst + (size_t)(brow + row) * 768 + cb + (c8 << 3)) = v;
    }
  } else {
    // f32 epilogue: two 128-row passes through LDS (128x256 f32 = 128KB)
    float* smf = (float*)smem;
#pragma unroll
    for (int p = 0; p < 2; ++p) {
      if (p) __syncthreads();
      if (wr == p) {
#pragma unroll
        for (int mi = 0; mi < 8; ++mi)
#pragma unroll
          for (int nj = 0; nj < 4; ++nj) {
            const int colb = (wc << 6) + (nj << 4) + l15;
            const float bb = bias[bcol + colb];
            const int row0 = (mi << 4) + ((lane >> 4) << 2);
#pragma unroll
            for (int rr = 0; rr < 4; ++rr)
              smf[(row0 + rr) * 256 + colb] = acc[mi][nj][rr] + bb;
          }
      }
      __syncthreads();
#pragma unroll
      for (int it = 0; it < 16; ++it) {
        const int f = (it << 9) + tid;
        const int row = f >> 6, c16 = f & 63;
        float4 v = *(const float4*)(smf + row * 256 + (c16 << 2));
        *(float4*)(dF + (size_t)(brow + (p << 7) + row) * 768 + bcol + (c16 << 2)) = v;
      }
    }
  }
}

// ---------------- Window attention: one block per (window, head) ----------------
__global__ __launch_bounds__(256, 4)
void win_attn(const u16* __restrict__ Qg, const u16* __restrict__ Kg,
              const u16* __restrict__ Vg, u16* __restrict__ Og) {
  __shared__ u16 Qs[64 * 72], Ks[64 * 72], Vt[64 * 72], Ps[64 * 72];
  const int cpx = gridDim.x >> 3;
  int bid = blockIdx.x;
  bid = (bid & 7) * cpx + (bid >> 3);
  const int h = bid % HEADS;
  const int gw = bid / HEADS;
  const size_t base = (size_t)gw * WIN * EMBED + (size_t)h * DH;
  const int tid = threadIdx.x;
  const int wid = tid >> 6, lane = tid & 63;

#pragma unroll
  for (int cc = 0; cc < 2; ++cc) {
    const int c = tid + (cc << 8);
    const int row = c >> 3, col8 = c & 7;
    const size_t goff = base + (size_t)row * EMBED + (col8 << 3);
    uint4 q4 = *(const uint4*)(Qg + goff);
    uint4 k4 = *(const uint4*)(Kg + goff);
    uint4 v4 = *(const uint4*)(Vg + goff);
    *(uint4*)(Qs + row * 72 + (col8 << 3)) = q4;
    *(uint4*)(Ks + row * 72 + (col8 << 3)) = k4;
    const u16* vp = (const u16*)&v4;
#pragma unroll
    for (int j = 0; j < 8; ++j)
      Vt[((col8 << 3) + j) * 72 + row] = vp[j];
  }
  __syncthreads();

  f32x4 sacc[4];
#pragma unroll
  for (int t = 0; t < 4; ++t) sacc[t] = (f32x4){0.f, 0.f, 0.f, 0.f};
  const int arow = (wid << 4) + (lane & 15);
  const int kb = ((lane >> 4) << 3);
  bf16x8 qf0 = *(const bf16x8*)(Qs + arow * 72 + kb);
  bf16x8 qf1 = *(const bf16x8*)(Qs + arow * 72 + 32 + kb);
#pragma unroll
  for (int t = 0; t < 4; ++t) {
    const int krow = (t << 4) + (lane & 15);
    bf16x8 kf0 = *(const bf16x8*)(Ks + krow * 72 + kb);
    bf16x8 kf1 = *(const bf16x8*)(Ks + krow * 72 + 32 + kb);
    sacc[t] = __builtin_amdgcn_mfma_f32_16x16x32_bf16(qf0, kf0, sacc[t], 0, 0, 0);
    sacc[t] = __builtin_amdgcn_mfma_f32_16x16x32_bf16(qf1, kf1, sacc[t], 0, 0, 0);
  }

#pragma unroll
  for (int t = 0; t < 4; ++t)
#pragma unroll
    for (int r = 0; r < 4; ++r) sacc[t][r] *= 0.125f;

#pragma unroll
  for (int r = 0; r < 4; ++r) {
    float m0 = fmaxf(fmaxf(sacc[0][r], sacc[1][r]), fmaxf(sacc[2][r], sacc[3][r]));
#pragma unroll
    for (int msk = 1; msk < 16; msk <<= 1) m0 = fmaxf(m0, __shfl_xor(m0, msk));
    float s0 = 0.f;
#pragma unroll
    for (int t = 0; t < 4; ++t) {
      float e = __expf(sacc[t][r] - m0);
      sacc[t][r] = e;
      s0 += e;
    }
#pragma unroll
    for (int msk = 1; msk < 16; msk <<= 1) s0 += __shfl_xor(s0, msk);
    const float inv = 1.f / s0;
#pragma unroll
    for (int t = 0; t < 4; ++t) sacc[t][r] *= inv;
  }

#pragma unroll
  for (int t = 0; t < 4; ++t)
#pragma unroll
    for (int r = 0; r < 4; ++r)
      Ps[((wid << 4) + ((lane >> 4) << 2) + r) * 72 + (t << 4) + (lane & 15)] = f2bf(sacc[t][r]);

  f32x4 oacc[4];
#pragma unroll
  for (int t = 0; t < 4; ++t) oacc[t] = (f32x4){0.f, 0.f, 0.f, 0.f};
  const int prow = (wid << 4) + (lane & 15);
  bf16x8 pf0 = *(const bf16x8*)(Ps + prow * 72 + kb);
  bf16x8 pf1 = *(const bf16x8*)(Ps + prow * 72 + 32 + kb);
#pragma unroll
  for (int t = 0; t < 4; ++t) {
    const int vrow = (t << 4) + (lane & 15);
    bf16x8 vf0 = *(const bf16x8*)(Vt + vrow * 72 + kb);
    bf16x8 vf1 = *(const bf16x8*)(Vt + vrow * 72 + 32 + kb);
    oacc[t] = __builtin_amdgcn_mfma_f32_16x16x32_bf16(pf0, vf0, oacc[t], 0, 0, 0);
    oacc[t] = __builtin_amdgcn_mfma_f32_16x16x32_bf16(pf1, vf1, oacc[t], 0, 0, 0);
  }

#pragma unroll
  for (int t = 0; t < 4; ++t)
#pragma unroll
    for (int r = 0; r < 4; ++r) {
      const int row = (wid << 4) + ((lane >> 4) << 2) + r;
      const int col = (t << 4) + (lane & 15);
      Og[base + (size_t)row * EMBED + col] = f2bf(oacc[t][r]);
    }
}

extern "C" void kernel_launch(void* const* d_in, const int* in_sizes, int n_in,
                              void* d_out, int out_size, void* d_ws, size_t ws_size,
                              hipStream_t stream) {
  const float* q  = (const float*)d_in[0];
  const float* Wq = (const float*)d_in[3];
  const float* bq = (const float*)d_in[4];
  const float* Wk = (const float*)d_in[5];
  const float* bk = (const float*)d_in[6];
  const float* Wv = (const float*)d_in[7];
  const float* bv = (const float*)d_in[8];
  const float* Wo = (const float*)d_in[9];
  const float* bo = (const float*)d_in[10];

  const int C = EMBED;
  const int M = in_sizes[0] / C;                 // 32768
  const size_t xsz = (size_t)M * C;
  const size_t wsz = (size_t)C * C;

  u16* Xb = (u16*)d_out;                         // scratch (overwritten by Wo GEMM)
  u16* Qb = (u16*)d_ws;
  u16* Kb = Qb + xsz;
  u16* Vb = Kb + xsz;
  u16* Wqkv = Vb + xsz;
  u16* Wob = Wqkv + 3 * wsz;
  float* biasc = (float*)(Wob + wsz);

  {
    int n4 = (int)(xsz >> 2);
    cvt_f32_bf16<<<(n4 + 255) / 256, 256, 0, stream>>>(q, Xb, n4);
    int w4 = (int)(wsz >> 2);
    cvt_f32_bf16<<<(w4 + 255) / 256, 256, 0, stream>>>(Wq, Wqkv, w4);
    cvt_f32_bf16<<<(w4 + 255) / 256, 256, 0, stream>>>(Wk, Wqkv + wsz, w4);
    cvt_f32_bf16<<<(w4 + 255) / 256, 256, 0, stream>>>(Wv, Wqkv + 2 * wsz, w4);
    cvt_f32_bf16<<<(w4 + 255) / 256, 256, 0, stream>>>(Wo, Wob, w4);
    concat_bias<<<9, 256, 0, stream>>>(bq, bk, bv, biasc);
  }

  // Fused QKV: [32768 x 2304] = X * Wqkv^T
  gemm256<false><<<(M / 256) * (2304 / 256), 512, 0, stream>>>(
      Xb, Wqkv, biasc, Qb, Kb, Vb, nullptr, 2304);

  win_attn<<<(M / WIN) * HEADS, 256, 0, stream>>>(Qb, Kb, Vb, Qb);

  // Output projection (f32 out)
  gemm256<true><<<(M / 256) * (C / 256), 512, 0, stream>>>(
      Qb, Wob, bo, nullptr, nullptr, nullptr, (float*)d_out, C);
}

// Round 4
// 256.990 us; speedup vs baseline: 1.0923x; 1.0923x over previous
//
#include <hip/hip_runtime.h>
#include <hip/hip_bf16.h>

#define EMBED 768
#define HEADS 12
#define WIN 64
#define DH 64
#define KDIM 768
#define NTILE 12      // KDIM / 64

typedef unsigned short u16;
typedef unsigned int u32;
typedef __attribute__((ext_vector_type(8))) short bf16x8;
typedef __attribute__((ext_vector_type(4))) float f32x4;

__device__ __forceinline__ u16 f2bf(float f) {
  union { float f; u32 u; } x; x.f = f;
  return (u16)((x.u + 0x7fffu + ((x.u >> 16) & 1u)) >> 16);
}

// ---------------- fp32 -> bf16 convert ----------------
__global__ void cvt_f32_bf16(const float* __restrict__ in, u16* __restrict__ out, int n4) {
  int i = blockIdx.x * blockDim.x + threadIdx.x;
  if (i >= n4) return;
  float4 v = ((const float4*)in)[i];
  ushort4 o;
  o.x = f2bf(v.x); o.y = f2bf(v.y); o.z = f2bf(v.z); o.w = f2bf(v.w);
  ((ushort4*)out)[i] = o;
}

__global__ void concat_bias(const float* __restrict__ bq, const float* __restrict__ bk,
                            const float* __restrict__ bv, float* __restrict__ out) {
  int i = blockIdx.x * 256 + threadIdx.x;
  if (i < 768) out[i] = bq[i];
  else if (i < 1536) out[i] = bk[i - 768];
  else if (i < 2304) out[i] = bv[i - 1536];
}

// ---------------- 256xBN pipelined NT GEMM (K=768), register read-ahead ----------------
// BM=256, BN=BNW*64, BK=64, 512 thr = 8 waves (2M x 4N); per-wave 128 x BNW*16.
// 2 barriers per K-tile (boundary only). A-frags reg-double-buffered one phase
// ahead; B-frags read once per tile. T1 swizzle, T2 XOR-LDS, T4 counted waits,
// T5 setprio.
template<int BNW, bool OUT_F32>
__global__ __launch_bounds__(512, 1)
void gemm256(const u16* __restrict__ A, const u16* __restrict__ Bw,
             const float* __restrict__ bias,
             u16* __restrict__ dQ, u16* __restrict__ dK, u16* __restrict__ dV,
             float* __restrict__ dF, int N) {
  constexpr int BN = BNW * 64;
  constexpr int BBUF = BN * 128;                 // bytes per B K-tile
  __shared__ char sc_[65536 + 2 * BBUF];
  const int tid = threadIdx.x;
  const int lane = tid & 63;
  const int wid = tid >> 6;
  const int wr = wid >> 2, wc = wid & 3;
  const int l15 = lane & 15;

  const int nbx = N / BN;
  const int cpx = gridDim.x >> 3;
  int bid = blockIdx.x;
  bid = (bid & 7) * cpx + (bid >> 3);            // bijective: grid % 8 == 0
  const int brow = (bid / nbx) << 8;
  const int bcol = (bid % nbx) * BN;

  // staging source (per-thread), pre-swizzled global col (T2, rule 21)
  const int srow = tid >> 3;
  const int scol = ((tid & 7) ^ (srow & 7)) << 3;
  const u16* Asrc = A + (size_t)(brow + srow) * KDIM + scol;
  const u16* Bsrc = Bw + (size_t)(bcol + srow) * KDIM + scol;
  const int lds_woff = wid << 10;

  auto STAGE = [&](int b, int kt) {
    char* ab = sc_ + b * 32768;
    char* bb = sc_ + 65536 + b * BBUF;
#pragma unroll
    for (int i = 0; i < 4; ++i)
      __builtin_amdgcn_global_load_lds(
          (const __attribute__((address_space(1))) void*)(Asrc + (size_t)(i << 6) * KDIM + kt),
          (__attribute__((address_space(3))) void*)(ab + (i << 13) + lds_woff), 16, 0, 0);
#pragma unroll
    for (int i = 0; i < BNW; ++i)
      __builtin_amdgcn_global_load_lds(
          (const __attribute__((address_space(1))) void*)(Bsrc + (size_t)(i << 6) * KDIM + kt),
          (__attribute__((address_space(3))) void*)(bb + (i << 13) + lds_woff), 16, 0, 0);
  };

  // swizzled frag-read offsets: koff0/koff1 select kk half; row&7 == lane&7
  const int koff0 = ((lane >> 4) << 4) ^ ((lane & 7) << 4);
  const int koff1 = koff0 ^ 64;

  f32x4 acc[8][BNW];
#pragma unroll
  for (int m = 0; m < 8; ++m)
#pragma unroll
    for (int n = 0; n < BNW; ++n) acc[m][n] = (f32x4){0.f, 0.f, 0.f, 0.f};

  bf16x8 RA[2][4];                               // [set][2 rows x 2 kk]
  bf16x8 RB[BNW][2];                             // per-tile B frags

  // A-frag LDS address for (buffer b, m-frag mi, kk-offset)
  auto pA = [&](int b, int mi, int koff) -> const char* {
    return sc_ + b * 32768 + (wr << 14) + mi * 2048 + l15 * 128 + koff;
  };
  auto pB = [&](int b, int nj, int koff) -> const char* {
    return sc_ + 65536 + b * BBUF + wc * (BNW * 2048) + nj * 2048 + l15 * 128 + koff;
  };

  // ---- prologue ----
  STAGE(0, 0);
  STAGE(1, 64);
  if constexpr (BNW == 4) asm volatile("s_waitcnt vmcnt(8)" ::: "memory");
  else                    asm volatile("s_waitcnt vmcnt(6)" ::: "memory");
  __builtin_amdgcn_sched_barrier(0);
  __builtin_amdgcn_s_barrier();
  // initial reads: tile 0, quadrant 0 + B
  RA[0][0] = *(const bf16x8*)pA(0, 0, koff0);
  RA[0][1] = *(const bf16x8*)pA(0, 0, koff1);
  RA[0][2] = *(const bf16x8*)pA(0, 1, koff0);
  RA[0][3] = *(const bf16x8*)pA(0, 1, koff1);
#pragma unroll
  for (int nj = 0; nj < BNW; ++nj) {
    RB[nj][0] = *(const bf16x8*)pB(0, nj, koff0);
    RB[nj][1] = *(const bf16x8*)pB(0, nj, koff1);
  }

#pragma unroll 2
  for (int t = 0; t < NTILE; ++t) {
    const int b = t & 1;
    // ---- phases q=0,1,2: read-ahead next quadrant, MFMA current ----
#pragma unroll
    for (int q = 0; q < 3; ++q) {
      const int s = q & 1, s1 = s ^ 1;
      RA[s1][0] = *(const bf16x8*)pA(b, 2 * q + 2, koff0);
      RA[s1][1] = *(const bf16x8*)pA(b, 2 * q + 2, koff1);
      RA[s1][2] = *(const bf16x8*)pA(b, 2 * q + 3, koff0);
      RA[s1][3] = *(const bf16x8*)pA(b, 2 * q + 3, koff1);
      __builtin_amdgcn_sched_barrier(0);
      __builtin_amdgcn_s_setprio(1);
#pragma unroll
      for (int nj = 0; nj < BNW; ++nj) {
        acc[2 * q][nj]     = __builtin_amdgcn_mfma_f32_16x16x32_bf16(RA[s][0], RB[nj][0], acc[2 * q][nj], 0, 0, 0);
        acc[2 * q][nj]     = __builtin_amdgcn_mfma_f32_16x16x32_bf16(RA[s][1], RB[nj][1], acc[2 * q][nj], 0, 0, 0);
        acc[2 * q + 1][nj] = __builtin_amdgcn_mfma_f32_16x16x32_bf16(RA[s][2], RB[nj][0], acc[2 * q + 1][nj], 0, 0, 0);
        acc[2 * q + 1][nj] = __builtin_amdgcn_mfma_f32_16x16x32_bf16(RA[s][3], RB[nj][1], acc[2 * q + 1][nj], 0, 0, 0);
      }
      __builtin_amdgcn_s_setprio(0);
    }
    // ---- phase q=3: tile boundary ----
    asm volatile("s_waitcnt vmcnt(0)" ::: "memory");   // tile t+1 stage landed (own)
    __builtin_amdgcn_sched_barrier(0);
    __builtin_amdgcn_s_barrier();                      // all waves' t+1 landed
    if (t + 1 < NTILE) {
      RA[0][0] = *(const bf16x8*)pA(b ^ 1, 0, koff0);  // tile t+1, quadrant 0
      RA[0][1] = *(const bf16x8*)pA(b ^ 1, 0, koff1);
      RA[0][2] = *(const bf16x8*)pA(b ^ 1, 1, koff0);
      RA[0][3] = *(const bf16x8*)pA(b ^ 1, 1, koff1);
      asm volatile("s_waitcnt lgkmcnt(4)" ::: "memory");  // q3's RA (set 1) done
    } else {
      asm volatile("s_waitcnt lgkmcnt(0)" ::: "memory");
    }
    __builtin_amdgcn_sched_barrier(0);
    __builtin_amdgcn_s_barrier();                      // all waves done reading buffer b
    if (t + 2 < NTILE) STAGE(b, (t + 2) << 6);         // safe to overwrite b now
    __builtin_amdgcn_s_setprio(1);
#pragma unroll
    for (int nj = 0; nj < BNW; ++nj) {
      acc[6][nj] = __builtin_amdgcn_mfma_f32_16x16x32_bf16(RA[1][0], RB[nj][0], acc[6][nj], 0, 0, 0);
      acc[6][nj] = __builtin_amdgcn_mfma_f32_16x16x32_bf16(RA[1][1], RB[nj][1], acc[6][nj], 0, 0, 0);
      acc[7][nj] = __builtin_amdgcn_mfma_f32_16x16x32_bf16(RA[1][2], RB[nj][0], acc[7][nj], 0, 0, 0);
      acc[7][nj] = __builtin_amdgcn_mfma_f32_16x16x32_bf16(RA[1][3], RB[nj][1], acc[7][nj], 0, 0, 0);
    }
    __builtin_amdgcn_s_setprio(0);
    if (t + 1 < NTILE) {                               // B for tile t+1 (WAR after MFMA)
#pragma unroll
      for (int nj = 0; nj < BNW; ++nj) {
        RB[nj][0] = *(const bf16x8*)pB(b ^ 1, nj, koff0);
        RB[nj][1] = *(const bf16x8*)pB(b ^ 1, nj, koff1);
      }
    }
  }

  u16* smem = (u16*)sc_;
  if constexpr (!OUT_F32) {
    // bf16 epilogue: stage 256x256 tile, coalesced 16B stores, QKV 3-way split
    __builtin_amdgcn_s_barrier();
#pragma unroll
    for (int mi = 0; mi < 8; ++mi)
#pragma unroll
      for (int nj = 0; nj < BNW; ++nj) {
        const int colb = (wc << 6) + (nj << 4) + l15;
        const float bb = bias[bcol + colb];
        const int row0 = (wr << 7) + (mi << 4) + ((lane >> 4) << 2);
#pragma unroll
        for (int rr = 0; rr < 4; ++rr)
          smem[((row0 + rr) << 8) + colb] = f2bf(acc[mi][nj][rr] + bb);
      }
    __syncthreads();
    const int seg = bcol / 768;
    const int cb = bcol - seg * 768;
    u16* dst = (seg == 0) ? dQ : (seg == 1) ? dK : dV;
#pragma unroll
    for (int it = 0; it < 16; ++it) {
      const int f = (it << 9) + tid;
      const int row = f >> 5, c8 = f & 31;
      uint4 v = *(const uint4*)(smem + (row << 8) + (c8 << 3));
      *(uint4*)(dst + (size_t)(brow + row) * 768 + cb + (c8 << 3)) = v;
    }
  } else {
    // f32 epilogue: two 128-row passes via LDS (128 x BN f32)
    float* smf = (float*)sc_;
    __builtin_amdgcn_s_barrier();
#pragma unroll
    for (int p = 0; p < 2; ++p) {
      if (p) __syncthreads();
      if (wr == p) {
#pragma unroll
        for (int mi = 0; mi < 8; ++mi)
#pragma unroll
          for (int nj = 0; nj < BNW; ++nj) {
            const int colb = wc * (BNW << 4) + (nj << 4) + l15;
            const float bb = bias[bcol + colb];
            const int row0 = (mi << 4) + ((lane >> 4) << 2);
#pragma unroll
            for (int rr = 0; rr < 4; ++rr)
              smf[(row0 + rr) * BN + colb] = acc[mi][nj][rr] + bb;
          }
      }
      __syncthreads();
      constexpr int QPR = BN / 4;                // float4 per row
#pragma unroll
      for (int it = 0; it < (128 * QPR) / 512; ++it) {
        const int f = (it << 9) + tid;
        const int row = f / QPR, c4 = f % QPR;
        float4 v = *(const float4*)(smf + row * BN + (c4 << 2));
        *(float4*)(dF + (size_t)(brow + (p << 7) + row) * N + bcol + (c4 << 2)) = v;
      }
    }
  }
}

// ---------------- Window attention: one block per (window, head) ----------------
__global__ __launch_bounds__(256, 4)
void win_attn(const u16* __restrict__ Qg, const u16* __restrict__ Kg,
              const u16* __restrict__ Vg, u16* __restrict__ Og) {
  __shared__ u16 Qs[64 * 72], Ks[64 * 72], Vt[64 * 72], Ps[64 * 72];
  const int cpx = gridDim.x >> 3;
  int bid = blockIdx.x;
  bid = (bid & 7) * cpx + (bid >> 3);
  const int h = bid % HEADS;
  const int gw = bid / HEADS;
  const size_t base = (size_t)gw * WIN * EMBED + (size_t)h * DH;
  const int tid = threadIdx.x;
  const int wid = tid >> 6, lane = tid & 63;

#pragma unroll
  for (int cc = 0; cc < 2; ++cc) {
    const int c = tid + (cc << 8);
    const int row = c >> 3, col8 = c & 7;
    const size_t goff = base + (size_t)row * EMBED + (col8 << 3);
    uint4 q4 = *(const uint4*)(Qg + goff);
    uint4 k4 = *(const uint4*)(Kg + goff);
    uint4 v4 = *(const uint4*)(Vg + goff);
    *(uint4*)(Qs + row * 72 + (col8 << 3)) = q4;
    *(uint4*)(Ks + row * 72 + (col8 << 3)) = k4;
    const u16* vp = (const u16*)&v4;
#pragma unroll
    for (int j = 0; j < 8; ++j)
      Vt[((col8 << 3) + j) * 72 + row] = vp[j];
  }
  __syncthreads();

  f32x4 sacc[4];
#pragma unroll
  for (int t = 0; t < 4; ++t) sacc[t] = (f32x4){0.f, 0.f, 0.f, 0.f};
  const int arow = (wid << 4) + (lane & 15);
  const int kb = ((lane >> 4) << 3);
  bf16x8 qf0 = *(const bf16x8*)(Qs + arow * 72 + kb);
  bf16x8 qf1 = *(const bf16x8*)(Qs + arow * 72 + 32 + kb);
#pragma unroll
  for (int t = 0; t < 4; ++t) {
    const int krow = (t << 4) + (lane & 15);
    bf16x8 kf0 = *(const bf16x8*)(Ks + krow * 72 + kb);
    bf16x8 kf1 = *(const bf16x8*)(Ks + krow * 72 + 32 + kb);
    sacc[t] = __builtin_amdgcn_mfma_f32_16x16x32_bf16(qf0, kf0, sacc[t], 0, 0, 0);
    sacc[t] = __builtin_amdgcn_mfma_f32_16x16x32_bf16(qf1, kf1, sacc[t], 0, 0, 0);
  }

#pragma unroll
  for (int t = 0; t < 4; ++t)
#pragma unroll
    for (int r = 0; r < 4; ++r) sacc[t][r] *= 0.125f;

#pragma unroll
  for (int r = 0; r < 4; ++r) {
    float m0 = fmaxf(fmaxf(sacc[0][r], sacc[1][r]), fmaxf(sacc[2][r], sacc[3][r]));
#pragma unroll
    for (int msk = 1; msk < 16; msk <<= 1) m0 = fmaxf(m0, __shfl_xor(m0, msk));
    float s0 = 0.f;
#pragma unroll
    for (int t = 0; t < 4; ++t) {
      float e = __expf(sacc[t][r] - m0);
      sacc[t][r] = e;
      s0 += e;
    }
#pragma unroll
    for (int msk = 1; msk < 16; msk <<= 1) s0 += __shfl_xor(s0, msk);
    const float inv = 1.f / s0;
#pragma unroll
    for (int t = 0; t < 4; ++t) sacc[t][r] *= inv;
  }

#pragma unroll
  for (int t = 0; t < 4; ++t)
#pragma unroll
    for (int r = 0; r < 4; ++r)
      Ps[((wid << 4) + ((lane >> 4) << 2) + r) * 72 + (t << 4) + (lane & 15)] = f2bf(sacc[t][r]);

  f32x4 oacc[4];
#pragma unroll
  for (int t = 0; t < 4; ++t) oacc[t] = (f32x4){0.f, 0.f, 0.f, 0.f};
  const int prow = (wid << 4) + (lane & 15);
  bf16x8 pf0 = *(const bf16x8*)(Ps + prow * 72 + kb);
  bf16x8 pf1 = *(const bf16x8*)(Ps + prow * 72 + 32 + kb);
#pragma unroll
  for (int t = 0; t < 4; ++t) {
    const int vrow = (t << 4) + (lane & 15);
    bf16x8 vf0 = *(const bf16x8*)(Vt + vrow * 72 + kb);
    bf16x8 vf1 = *(const bf16x8*)(Vt + vrow * 72 + 32 + kb);
    oacc[t] = __builtin_amdgcn_mfma_f32_16x16x32_bf16(pf0, vf0, oacc[t], 0, 0, 0);
    oacc[t] = __builtin_amdgcn_mfma_f32_16x16x32_bf16(pf1, vf1, oacc[t], 0, 0, 0);
  }

#pragma unroll
  for (int t = 0; t < 4; ++t)
#pragma unroll
    for (int r = 0; r < 4; ++r) {
      const int row = (wid << 4) + ((lane >> 4) << 2) + r;
      const int col = (t << 4) + (lane & 15);
      Og[base + (size_t)row * EMBED + col] = f2bf(oacc[t][r]);
    }
}

extern "C" void kernel_launch(void* const* d_in, const int* in_sizes, int n_in,
                              void* d_out, int out_size, void* d_ws, size_t ws_size,
                              hipStream_t stream) {
  const float* q  = (const float*)d_in[0];
  const float* Wq = (const float*)d_in[3];
  const float* bq = (const float*)d_in[4];
  const float* Wk = (const float*)d_in[5];
  const float* bk = (const float*)d_in[6];
  const float* Wv = (const float*)d_in[7];
  const float* bv = (const float*)d_in[8];
  const float* Wo = (const float*)d_in[9];
  const float* bo = (const float*)d_in[10];

  const int C = EMBED;
  const int M = in_sizes[0] / C;                 // 32768
  const size_t xsz = (size_t)M * C;
  const size_t wsz = (size_t)C * C;

  u16* Xb = (u16*)d_out;                         // scratch (overwritten by Wo GEMM)
  u16* Qb = (u16*)d_ws;
  u16* Kb = Qb + xsz;
  u16* Vb = Kb + xsz;
  u16* Wqkv = Vb + xsz;
  u16* Wob = Wqkv + 3 * wsz;
  float* biasc = (float*)(Wob + wsz);

  {
    int n4 = (int)(xsz >> 2);
    cvt_f32_bf16<<<(n4 + 255) / 256, 256, 0, stream>>>(q, Xb, n4);
    int w4 = (int)(wsz >> 2);
    cvt_f32_bf16<<<(w4 + 255) / 256, 256, 0, stream>>>(Wq, Wqkv, w4);
    cvt_f32_bf16<<<(w4 + 255) / 256, 256, 0, stream>>>(Wk, Wqkv + wsz, w4);
    cvt_f32_bf16<<<(w4 + 255) / 256, 256, 0, stream>>>(Wv, Wqkv + 2 * wsz, w4);
    cvt_f32_bf16<<<(w4 + 255) / 256, 256, 0, stream>>>(Wo, Wob, w4);
    concat_bias<<<9, 256, 0, stream>>>(bq, bk, bv, biasc);
  }

  // Fused QKV: [32768 x 2304] = X * Wqkv^T  (grid 1152, %8==0)
  gemm256<4, false><<<(M / 256) * (2304 / 256), 512, 0, stream>>>(
      Xb, Wqkv, biasc, Qb, Kb, Vb, nullptr, 2304);

  win_attn<<<(M / WIN) * HEADS, 256, 0, stream>>>(Qb, Kb, Vb, Qb);

  // Output projection, BN=128: grid 128*6 = 768 = exactly 3 rounds
  gemm256<2, true><<<(M / 256) * (C / 128), 512, 0, stream>>>(
      Qb, Wob, bo, nullptr, nullptr, nullptr, (float*)d_out, C);
}

// Round 5
// 250.679 us; speedup vs baseline: 1.1199x; 1.0252x over previous
//
#include <hip/hip_runtime.h>
#include <hip/hip_bf16.h>

#define EMBED 768
#define HEADS 12
#define WIN 64
#define DH 64
#define KDIM 768
#define NTILE 12      // KDIM / 64

typedef unsigned short u16;
typedef unsigned int u32;
typedef __attribute__((ext_vector_type(8))) short bf16x8;
typedef __attribute__((ext_vector_type(4))) float f32x4;

__device__ __forceinline__ u16 f2bf(float f) {
  union { float f; u32 u; } x; x.f = f;
  return (u16)((x.u + 0x7fffu + ((x.u >> 16) & 1u)) >> 16);
}

// ---------------- fp32 -> bf16 convert ----------------
__global__ void cvt_f32_bf16(const float* __restrict__ in, u16* __restrict__ out, int n4) {
  int i = blockIdx.x * blockDim.x + threadIdx.x;
  if (i >= n4) return;
  float4 v = ((const float4*)in)[i];
  ushort4 o;
  o.x = f2bf(v.x); o.y = f2bf(v.y); o.z = f2bf(v.z); o.w = f2bf(v.w);
  ((ushort4*)out)[i] = o;
}

__global__ void concat_bias(const float* __restrict__ bq, const float* __restrict__ bk,
                            const float* __restrict__ bv, float* __restrict__ out) {
  int i = blockIdx.x * 256 + threadIdx.x;
  if (i < 768) out[i] = bq[i];
  else if (i < 1536) out[i] = bk[i - 768];
  else if (i < 2304) out[i] = bv[i - 1536];
}

// ---------------- 256xBN pipelined NT GEMM (K=768) ----------------
// BM=256, BN=BNW*64, BK=64, 512 thr = 8 waves (2M x 4N); per-wave 128 x BNW*16.
// Reg read-ahead (A one phase ahead, B once/tile). STAGE(t+2) issued at q2
// behind a buffer-release barrier; boundary waits counted vmcnt(#loads) so
// next-tile loads never drain (T4). 2 barriers/tile. T1/T2/T5 as before.
template<int BNW, bool OUT_F32>
__global__ __launch_bounds__(512, 1)
void gemm256(const u16* __restrict__ A, const u16* __restrict__ Bw,
             const float* __restrict__ bias,
             u16* __restrict__ dQ, u16* __restrict__ dK, u16* __restrict__ dV,
             float* __restrict__ dF, int N) {
  constexpr int BN = BNW * 64;
  constexpr int BBUF = BN * 128;                 // bytes per B K-tile
  __shared__ char sc_[65536 + 2 * BBUF];
  const int tid = threadIdx.x;
  const int lane = tid & 63;
  const int wid = tid >> 6;
  const int wr = wid >> 2, wc = wid & 3;
  const int l15 = lane & 15;

  const int nbx = N / BN;
  const int cpx = gridDim.x >> 3;
  int bid = blockIdx.x;
  bid = (bid & 7) * cpx + (bid >> 3);            // bijective: grid % 8 == 0
  const int brow = (bid / nbx) << 8;
  const int bcol = (bid % nbx) * BN;

  // staging source (per-thread), pre-swizzled global col (T2, rule 21)
  const int srow = tid >> 3;
  const int scol = ((tid & 7) ^ (srow & 7)) << 3;
  const u16* Asrc = A + (size_t)(brow + srow) * KDIM + scol;
  const u16* Bsrc = Bw + (size_t)(bcol + srow) * KDIM + scol;
  const int lds_woff = wid << 10;

  auto STAGE = [&](int b, int kt) {
    char* ab = sc_ + b * 32768;
    char* bb = sc_ + 65536 + b * BBUF;
#pragma unroll
    for (int i = 0; i < 4; ++i)
      __builtin_amdgcn_global_load_lds(
          (const __attribute__((address_space(1))) void*)(Asrc + (size_t)(i << 6) * KDIM + kt),
          (__attribute__((address_space(3))) void*)(ab + (i << 13) + lds_woff), 16, 0, 0);
#pragma unroll
    for (int i = 0; i < BNW; ++i)
      __builtin_amdgcn_global_load_lds(
          (const __attribute__((address_space(1))) void*)(Bsrc + (size_t)(i << 6) * KDIM + kt),
          (__attribute__((address_space(3))) void*)(bb + (i << 13) + lds_woff), 16, 0, 0);
  };

  // swizzled frag-read offsets: koff0/koff1 select kk half; row&7 == lane&7
  const int koff0 = ((lane >> 4) << 4) ^ ((lane & 7) << 4);
  const int koff1 = koff0 ^ 64;

  f32x4 acc[8][BNW];
#pragma unroll
  for (int m = 0; m < 8; ++m)
#pragma unroll
    for (int n = 0; n < BNW; ++n) acc[m][n] = (f32x4){0.f, 0.f, 0.f, 0.f};

  bf16x8 RA[2][4];
  bf16x8 RB[BNW][2];

  auto pA = [&](int b, int mi, int koff) -> const char* {
    return sc_ + b * 32768 + (wr << 14) + mi * 2048 + l15 * 128 + koff;
  };
  auto pB = [&](int b, int nj, int koff) -> const char* {
    return sc_ + 65536 + b * BBUF + wc * (BNW * 2048) + nj * 2048 + l15 * 128 + koff;
  };

  // ---- prologue: stage tiles 0,1; wait tile 0 only ----
  STAGE(0, 0);
  STAGE(1, 64);
  if constexpr (BNW == 4) asm volatile("s_waitcnt vmcnt(8)" ::: "memory");
  else                    asm volatile("s_waitcnt vmcnt(6)" ::: "memory");
  __builtin_amdgcn_sched_barrier(0);
  __builtin_amdgcn_s_barrier();
  RA[0][0] = *(const bf16x8*)pA(0, 0, koff0);
  RA[0][1] = *(const bf16x8*)pA(0, 0, koff1);
  RA[0][2] = *(const bf16x8*)pA(0, 1, koff0);
  RA[0][3] = *(const bf16x8*)pA(0, 1, koff1);
#pragma unroll
  for (int nj = 0; nj < BNW; ++nj) {
    RB[nj][0] = *(const bf16x8*)pB(0, nj, koff0);
    RB[nj][1] = *(const bf16x8*)pB(0, nj, koff1);
  }

#pragma unroll 2
  for (int t = 0; t < NTILE; ++t) {
    const int b = t & 1;
    // ---- phases q=0,1,2: read-ahead next quadrant, MFMA current ----
#pragma unroll
    for (int q = 0; q < 3; ++q) {
      const int s = q & 1, s1 = s ^ 1;
      RA[s1][0] = *(const bf16x8*)pA(b, 2 * q + 2, koff0);
      RA[s1][1] = *(const bf16x8*)pA(b, 2 * q + 2, koff1);
      RA[s1][2] = *(const bf16x8*)pA(b, 2 * q + 3, koff0);
      RA[s1][3] = *(const bf16x8*)pA(b, 2 * q + 3, koff1);
      if (q == 2 && t + 2 < NTILE) {
        __builtin_amdgcn_s_barrier();            // all waves done reading buf b
        STAGE(b, (t + 2) << 6);                  // full t+2 stage; lands under t+1 compute
      }
      __builtin_amdgcn_s_setprio(1);
#pragma unroll
      for (int nj = 0; nj < BNW; ++nj) {
        acc[2 * q][nj]     = __builtin_amdgcn_mfma_f32_16x16x32_bf16(RA[s][0], RB[nj][0], acc[2 * q][nj], 0, 0, 0);
        acc[2 * q][nj]     = __builtin_amdgcn_mfma_f32_16x16x32_bf16(RA[s][1], RB[nj][1], acc[2 * q][nj], 0, 0, 0);
        acc[2 * q + 1][nj] = __builtin_amdgcn_mfma_f32_16x16x32_bf16(RA[s][2], RB[nj][0], acc[2 * q + 1][nj], 0, 0, 0);
        acc[2 * q + 1][nj] = __builtin_amdgcn_mfma_f32_16x16x32_bf16(RA[s][3], RB[nj][1], acc[2 * q + 1][nj], 0, 0, 0);
      }
      __builtin_amdgcn_s_setprio(0);
    }
    // ---- tile boundary ----
    if (t + 1 < NTILE) {
      if (t + 2 < NTILE) {                       // counted: t+2's loads stay in flight
        if constexpr (BNW == 4) asm volatile("s_waitcnt vmcnt(8)" ::: "memory");
        else                    asm volatile("s_waitcnt vmcnt(6)" ::: "memory");
      } else {
        asm volatile("s_waitcnt vmcnt(0)" ::: "memory");
      }
      __builtin_amdgcn_sched_barrier(0);
      __builtin_amdgcn_s_barrier();              // t+1 landed for all waves
      RA[0][0] = *(const bf16x8*)pA(b ^ 1, 0, koff0);
      RA[0][1] = *(const bf16x8*)pA(b ^ 1, 0, koff1);
      RA[0][2] = *(const bf16x8*)pA(b ^ 1, 1, koff0);
      RA[0][3] = *(const bf16x8*)pA(b ^ 1, 1, koff1);
      asm volatile("s_waitcnt lgkmcnt(4)" ::: "memory");   // quadrant-3 RA done
      __builtin_amdgcn_sched_barrier(0);
    } else {
      asm volatile("s_waitcnt lgkmcnt(0)" ::: "memory");
      __builtin_amdgcn_sched_barrier(0);
    }
    __builtin_amdgcn_s_setprio(1);
#pragma unroll
    for (int nj = 0; nj < BNW; ++nj) {
      acc[6][nj] = __builtin_amdgcn_mfma_f32_16x16x32_bf16(RA[1][0], RB[nj][0], acc[6][nj], 0, 0, 0);
      acc[6][nj] = __builtin_amdgcn_mfma_f32_16x16x32_bf16(RA[1][1], RB[nj][1], acc[6][nj], 0, 0, 0);
      acc[7][nj] = __builtin_amdgcn_mfma_f32_16x16x32_bf16(RA[1][2], RB[nj][0], acc[7][nj], 0, 0, 0);
      acc[7][nj] = __builtin_amdgcn_mfma_f32_16x16x32_bf16(RA[1][3], RB[nj][1], acc[7][nj], 0, 0, 0);
    }
    __builtin_amdgcn_s_setprio(0);
    if (t + 1 < NTILE) {                         // B for tile t+1 (WAR-safe after MFMA)
#pragma unroll
      for (int nj = 0; nj < BNW; ++nj) {
        RB[nj][0] = *(const bf16x8*)pB(b ^ 1, nj, koff0);
        RB[nj][1] = *(const bf16x8*)pB(b ^ 1, nj, koff1);
      }
    }
  }

  u16* smem = (u16*)sc_;
  if constexpr (!OUT_F32) {
    // bf16 epilogue: stage 256x256 tile, coalesced 16B stores, QKV 3-way split
    __builtin_amdgcn_s_barrier();
#pragma unroll
    for (int mi = 0; mi < 8; ++mi)
#pragma unroll
      for (int nj = 0; nj < BNW; ++nj) {
        const int colb = (wc << 6) + (nj << 4) + l15;
        const float bb = bias[bcol + colb];
        const int row0 = (wr << 7) + (mi << 4) + ((lane >> 4) << 2);
#pragma unroll
        for (int rr = 0; rr < 4; ++rr)
          smem[((row0 + rr) << 8) + colb] = f2bf(acc[mi][nj][rr] + bb);
      }
    __syncthreads();
    const int seg = bcol / 768;
    const int cb = bcol - seg * 768;
    u16* dst = (seg == 0) ? dQ : (seg == 1) ? dK : dV;
#pragma unroll
    for (int it = 0; it < 16; ++it) {
      const int f = (it << 9) + tid;
      const int row = f >> 5, c8 = f & 31;
      uint4 v = *(const uint4*)(smem + (row << 8) + (c8 << 3));
      *(uint4*)(dst + (size_t)(brow + row) * 768 + cb + (c8 << 3)) = v;
    }
  } else {
    // f32 epilogue: two 128-row passes via LDS (128 x BN f32)
    float* smf = (float*)sc_;
    __builtin_amdgcn_s_barrier();
#pragma unroll
    for (int p = 0; p < 2; ++p) {
      if (p) __syncthreads();
      if (wr == p) {
#pragma unroll
        for (int mi = 0; mi < 8; ++mi)
#pragma unroll
          for (int nj = 0; nj < BNW; ++nj) {
            const int colb = wc * (BNW << 4) + (nj << 4) + l15;
            const float bb = bias[bcol + colb];
            const int row0 = (mi << 4) + ((lane >> 4) << 2);
#pragma unroll
            for (int rr = 0; rr < 4; ++rr)
              smf[(row0 + rr) * BN + colb] = acc[mi][nj][rr] + bb;
          }
      }
      __syncthreads();
      constexpr int QPR = BN / 4;
#pragma unroll
      for (int it = 0; it < (128 * QPR) / 512; ++it) {
        const int f = (it << 9) + tid;
        const int row = f / QPR, c4 = f % QPR;
        float4 v = *(const float4*)(smf + row * BN + (c4 << 2));
        *(float4*)(dF + (size_t)(brow + (p << 7) + row) * N + bcol + (c4 << 2)) = v;
      }
    }
  }
}

// ---------------- Window attention: one block per (window, head) ----------------
__global__ __launch_bounds__(256, 4)
void win_attn(const u16* __restrict__ Qg, const u16* __restrict__ Kg,
              const u16* __restrict__ Vg, u16* __restrict__ Og) {
  __shared__ u16 Qs[64 * 72], Ks[64 * 72], Vt[64 * 72], Ps[64 * 72];
  const int cpx = gridDim.x >> 3;
  int bid = blockIdx.x;
  bid = (bid & 7) * cpx + (bid >> 3);
  const int h = bid % HEADS;
  const int gw = bid / HEADS;
  const size_t base = (size_t)gw * WIN * EMBED + (size_t)h * DH;
  const int tid = threadIdx.x;
  const int wid = tid >> 6, lane = tid & 63;

#pragma unroll
  for (int cc = 0; cc < 2; ++cc) {
    const int c = tid + (cc << 8);
    const int row = c >> 3, col8 = c & 7;
    const size_t goff = base + (size_t)row * EMBED + (col8 << 3);
    uint4 q4 = *(const uint4*)(Qg + goff);
    uint4 k4 = *(const uint4*)(Kg + goff);
    uint4 v4 = *(const uint4*)(Vg + goff);
    *(uint4*)(Qs + row * 72 + (col8 << 3)) = q4;
    *(uint4*)(Ks + row * 72 + (col8 << 3)) = k4;
    const u16* vp = (const u16*)&v4;
#pragma unroll
    for (int j = 0; j < 8; ++j)
      Vt[((col8 << 3) + j) * 72 + row] = vp[j];
  }
  __syncthreads();

  f32x4 sacc[4];
#pragma unroll
  for (int t = 0; t < 4; ++t) sacc[t] = (f32x4){0.f, 0.f, 0.f, 0.f};
  const int arow = (wid << 4) + (lane & 15);
  const int kb = ((lane >> 4) << 3);
  bf16x8 qf0 = *(const bf16x8*)(Qs + arow * 72 + kb);
  bf16x8 qf1 = *(const bf16x8*)(Qs + arow * 72 + 32 + kb);
#pragma unroll
  for (int t = 0; t < 4; ++t) {
    const int krow = (t << 4) + (lane & 15);
    bf16x8 kf0 = *(const bf16x8*)(Ks + krow * 72 + kb);
    bf16x8 kf1 = *(const bf16x8*)(Ks + krow * 72 + 32 + kb);
    sacc[t] = __builtin_amdgcn_mfma_f32_16x16x32_bf16(qf0, kf0, sacc[t], 0, 0, 0);
    sacc[t] = __builtin_amdgcn_mfma_f32_16x16x32_bf16(qf1, kf1, sacc[t], 0, 0, 0);
  }

#pragma unroll
  for (int t = 0; t < 4; ++t)
#pragma unroll
    for (int r = 0; r < 4; ++r) sacc[t][r] *= 0.125f;

#pragma unroll
  for (int r = 0; r < 4; ++r) {
    float m0 = fmaxf(fmaxf(sacc[0][r], sacc[1][r]), fmaxf(sacc[2][r], sacc[3][r]));
#pragma unroll
    for (int msk = 1; msk < 16; msk <<= 1) m0 = fmaxf(m0, __shfl_xor(m0, msk));
    float s0 = 0.f;
#pragma unroll
    for (int t = 0; t < 4; ++t) {
      float e = __expf(sacc[t][r] - m0);
      sacc[t][r] = e;
      s0 += e;
    }
#pragma unroll
    for (int msk = 1; msk < 16; msk <<= 1) s0 += __shfl_xor(s0, msk);
    const float inv = 1.f / s0;
#pragma unroll
    for (int t = 0; t < 4; ++t) sacc[t][r] *= inv;
  }

#pragma unroll
  for (int t = 0; t < 4; ++t)
#pragma unroll
    for (int r = 0; r < 4; ++r)
      Ps[((wid << 4) + ((lane >> 4) << 2) + r) * 72 + (t << 4) + (lane & 15)] = f2bf(sacc[t][r]);

  f32x4 oacc[4];
#pragma unroll
  for (int t = 0; t < 4; ++t) oacc[t] = (f32x4){0.f, 0.f, 0.f, 0.f};
  const int prow = (wid << 4) + (lane & 15);
  bf16x8 pf0 = *(const bf16x8*)(Ps + prow * 72 + kb);
  bf16x8 pf1 = *(const bf16x8*)(Ps + prow * 72 + 32 + kb);
#pragma unroll
  for (int t = 0; t < 4; ++t) {
    const int vrow = (t << 4) + (lane & 15);
    bf16x8 vf0 = *(const bf16x8*)(Vt + vrow * 72 + kb);
    bf16x8 vf1 = *(const bf16x8*)(Vt + vrow * 72 + 32 + kb);
    oacc[t] = __builtin_amdgcn_mfma_f32_16x16x32_bf16(pf0, vf0, oacc[t], 0, 0, 0);
    oacc[t] = __builtin_amdgcn_mfma_f32_16x16x32_bf16(pf1, vf1, oacc[t], 0, 0, 0);
  }

#pragma unroll
  for (int t = 0; t < 4; ++t)
#pragma unroll
    for (int r = 0; r < 4; ++r) {
      const int row = (wid << 4) + ((lane >> 4) << 2) + r;
      const int col = (t << 4) + (lane & 15);
      Og[base + (size_t)row * EMBED + col] = f2bf(oacc[t][r]);
    }
}

extern "C" void kernel_launch(void* const* d_in, const int* in_sizes, int n_in,
                              void* d_out, int out_size, void* d_ws, size_t ws_size,
                              hipStream_t stream) {
  const float* q  = (const float*)d_in[0];
  const float* Wq = (const float*)d_in[3];
  const float* bq = (const float*)d_in[4];
  const float* Wk = (const float*)d_in[5];
  const float* bk = (const float*)d_in[6];
  const float* Wv = (const float*)d_in[7];
  const float* bv = (const float*)d_in[8];
  const float* Wo = (const float*)d_in[9];
  const float* bo = (const float*)d_in[10];

  const int C = EMBED;
  const int M = in_sizes[0] / C;                 // 32768
  const size_t xsz = (size_t)M * C;
  const size_t wsz = (size_t)C * C;

  u16* Xb = (u16*)d_out;                         // scratch (overwritten by Wo GEMM)
  u16* Qb = (u16*)d_ws;
  u16* Kb = Qb + xsz;
  u16* Vb = Kb + xsz;
  u16* Wqkv = Vb + xsz;
  u16* Wob = Wqkv + 3 * wsz;
  float* biasc = (float*)(Wob + wsz);

  {
    int n4 = (int)(xsz >> 2);
    cvt_f32_bf16<<<(n4 + 255) / 256, 256, 0, stream>>>(q, Xb, n4);
    int w4 = (int)(wsz >> 2);
    cvt_f32_bf16<<<(w4 + 255) / 256, 256, 0, stream>>>(Wq, Wqkv, w4);
    cvt_f32_bf16<<<(w4 + 255) / 256, 256, 0, stream>>>(Wk, Wqkv + wsz, w4);
    cvt_f32_bf16<<<(w4 + 255) / 256, 256, 0, stream>>>(Wv, Wqkv + 2 * wsz, w4);
    cvt_f32_bf16<<<(w4 + 255) / 256, 256, 0, stream>>>(Wo, Wob, w4);
    concat_bias<<<9, 256, 0, stream>>>(bq, bk, bv, biasc);
  }

  // Fused QKV: [32768 x 2304] = X * Wqkv^T  (grid 1152, %8==0)
  gemm256<4, false><<<(M / 256) * (2304 / 256), 512, 0, stream>>>(
      Xb, Wqkv, biasc, Qb, Kb, Vb, nullptr, 2304);

  win_attn<<<(M / WIN) * HEADS, 256, 0, stream>>>(Qb, Kb, Vb, Qb);

  // Output projection, BN=128: grid 128*6 = 768 = exactly 3 rounds
  gemm256<2, true><<<(M / 256) * (C / 128), 512, 0, stream>>>(
      Qb, Wob, bo, nullptr, nullptr, nullptr, (float*)d_out, C);
}